// Round 1
// baseline (197.072 us; speedup 1.0000x reference)
//
#include <hip/hip_runtime.h>
#include <hip/hip_bf16.h>

#define B_  8
#define S_  4096
#define DM  1024
#define DO  1024

typedef __attribute__((ext_vector_type(4))) float f32x4;
typedef __attribute__((ext_vector_type(8))) short bf16x8;

__device__ inline unsigned int pkbf(float a, float b) {
    __hip_bfloat162 h = __float22bfloat162_rn(float2{a, b});
    union { __hip_bfloat162 h2; unsigned int u; } cv;
    cv.h2 = h;
    return cv.u;
}

// ---- prep: W_pack[b][nb][ks][n:128][k:32] bf16 (pre-tiled, transposed) ----
// W_eff[b][i][o] = p0*W[i0][i][o] + p1*W[i1][i][o]; stored transposed per tile
// so GEMM B-staging is one contiguous 8KB chunk per (tile, k-step).
__global__ __launch_bounds__(256) void prep_wpack(
    const float* __restrict__ W, const int* __restrict__ sel_idx,
    const float* __restrict__ sel_probs, unsigned short* __restrict__ wpack)
{
    const int ks = blockIdx.x, nb = blockIdx.y, b = blockIdx.z;
    const int i0 = sel_idx[b*2+0], i1 = sel_idx[b*2+1];
    const float p0 = sel_probs[b*2+0], p1 = sel_probs[b*2+1];
    const int t = threadIdx.x;
    const int n  = t >> 1;          // 0..127 (output row within tile)
    const int kh = (t & 1) * 16;    // k half: 0 or 16
    const float* w0 = W + (size_t)i0 * DM * DO;
    const float* w1 = W + (size_t)i1 * DM * DO;
    const int ng = nb * 128 + n;

    unsigned short tmp[16] __attribute__((aligned(16)));
    #pragma unroll
    for (int j = 0; j < 16; j += 2) {
        const size_t kg0 = (size_t)(ks * 32 + kh + j);
        float v0 = p0 * w0[kg0 * DO + ng]       + p1 * w1[kg0 * DO + ng];
        float v1 = p0 * w0[(kg0 + 1) * DO + ng] + p1 * w1[(kg0 + 1) * DO + ng];
        *reinterpret_cast<unsigned int*>(&tmp[j]) = pkbf(v0, v1);
    }
    unsigned short* outp = wpack + ((((size_t)b * 8 + nb) * 32 + ks) * 128 + n) * 32 + kh;
    *reinterpret_cast<uint4*>(outp)     = *reinterpret_cast<const uint4*>(tmp);
    *reinterpret_cast<uint4*>(outp + 8) = *reinterpret_cast<const uint4*>(tmp + 8);
}

// ---- prep: b_eff[b][o] ----
__global__ __launch_bounds__(256) void prep_beff(
    const float* __restrict__ bias, const int* __restrict__ sel_idx,
    const float* __restrict__ sel_probs, float* __restrict__ beff)
{
    const int b = blockIdx.x;
    const int i0 = sel_idx[b*2+0], i1 = sel_idx[b*2+1];
    const float p0 = sel_probs[b*2+0], p1 = sel_probs[b*2+1];
    for (int o = threadIdx.x; o < DO; o += blockDim.x)
        beff[(size_t)b * DO + o] = p0 * bias[(size_t)i0 * DO + o]
                                 + p1 * bias[(size_t)i1 * DO + o];
}

// ---- GEMM: per-batch (4096x1024) @ W_eff (1024x1024), bias + sigmoid ----
// 128x128 tile, BK=32, 4 waves (2x2), mfma_f32_16x16x32_bf16.
__global__ __launch_bounds__(256, 2) void gemm_bias_sigmoid(
    const float* __restrict__ X, const unsigned short* __restrict__ wpack,
    const float* __restrict__ beff, float* __restrict__ out)
{
    __shared__ unsigned short As[128 * 32];  // [row s][k] bf16, 8KB
    __shared__ unsigned short Bs[128 * 32];  // [col o][k] bf16, 8KB

    const int nb = blockIdx.x;   // fastest dim -> nb pins to XCD for W_pack L2 reuse
    const int bm = blockIdx.y;
    const int b  = blockIdx.z;
    const int t = threadIdx.x;
    const int wave = t >> 6, lane = t & 63;
    const int wm = wave >> 1, wn = wave & 1;   // 2x2 wave grid, 64x64 each
    const int fr = lane & 15, fq = lane >> 4;

    const float* Xb = X + ((size_t)b * S_ + (size_t)bm * 128) * DM;
    const unsigned short* Wb = wpack + (((size_t)b * 8 + nb) * 32) * 4096;

    // A staging: thread t covers As elements [t*8, t*8+8) (row t/4, k (t%4)*8)
    // in chunk0 (rows 0..63) and the same position in chunk1 (rows 64..127).
    const int ar = t >> 2;
    const int ak = (t & 3) * 8;
    const float* a_src = Xb + (size_t)ar * DM + ak;

    f32x4 acc[4][4] = {};

    for (int ks = 0; ks < 32; ++ks) {
        // ---- stage B: contiguous 8KB tile via global_load_lds (2 x 4KB) ----
        const char* gB = (const char*)(Wb + (size_t)ks * 4096);
        __builtin_amdgcn_global_load_lds(
            (const __attribute__((address_space(1))) void*)(gB + wave * 1024 + lane * 16),
            (__attribute__((address_space(3))) void*)((char*)Bs + wave * 1024),
            16, 0, 0);
        __builtin_amdgcn_global_load_lds(
            (const __attribute__((address_space(1))) void*)(gB + 4096 + wave * 1024 + lane * 16),
            (__attribute__((address_space(3))) void*)((char*)Bs + 4096 + wave * 1024),
            16, 0, 0);

        // ---- stage A: fp32 -> bf16, lane-contiguous ds_write_b128 ----
        const float* s0 = a_src + ks * 32;
        const float* s1 = s0 + (size_t)64 * DM;
        float4 x0 = *reinterpret_cast<const float4*>(s0);
        float4 x1 = *reinterpret_cast<const float4*>(s0 + 4);
        float4 x2 = *reinterpret_cast<const float4*>(s1);
        float4 x3 = *reinterpret_cast<const float4*>(s1 + 4);
        uint4 pk0, pk1;
        pk0.x = pkbf(x0.x, x0.y); pk0.y = pkbf(x0.z, x0.w);
        pk0.z = pkbf(x1.x, x1.y); pk0.w = pkbf(x1.z, x1.w);
        pk1.x = pkbf(x2.x, x2.y); pk1.y = pkbf(x2.z, x2.w);
        pk1.z = pkbf(x3.x, x3.y); pk1.w = pkbf(x3.z, x3.w);
        *reinterpret_cast<uint4*>((char*)As + t * 16)        = pk0;
        *reinterpret_cast<uint4*>((char*)As + 4096 + t * 16) = pk1;

        __syncthreads();

        bf16x8 af[4], bfr[4];
        #pragma unroll
        for (int m = 0; m < 4; ++m)
            af[m] = *reinterpret_cast<const bf16x8*>(As + (wm * 64 + m * 16 + fr) * 32 + fq * 8);
        #pragma unroll
        for (int n = 0; n < 4; ++n)
            bfr[n] = *reinterpret_cast<const bf16x8*>(Bs + (wn * 64 + n * 16 + fr) * 32 + fq * 8);
        #pragma unroll
        for (int m = 0; m < 4; ++m) {
            #pragma unroll
            for (int n = 0; n < 4; ++n)
                acc[m][n] = __builtin_amdgcn_mfma_f32_16x16x32_bf16(af[m], bfr[n], acc[m][n], 0, 0, 0);
        }

        __syncthreads();
    }

    // ---- epilogue: bias + sigmoid, fp32 store ----
    // C/D frag layout: col = lane&15, row = (lane>>4)*4 + reg   [m89/m91]
    const float* be = beff + (size_t)b * DO + nb * 128;
    float* outb = out + ((size_t)b * S_ + (size_t)bm * 128) * DO + nb * 128;
    #pragma unroll
    for (int n = 0; n < 4; ++n) {
        const int col = wn * 64 + n * 16 + fr;
        const float bv = be[col];
        #pragma unroll
        for (int m = 0; m < 4; ++m) {
            const int row0 = wm * 64 + m * 16 + fq * 4;
            #pragma unroll
            for (int r = 0; r < 4; ++r) {
                float xv = acc[m][n][r] + bv;
                outb[(size_t)(row0 + r) * DO + col] = 1.0f / (1.0f + __expf(-xv));
            }
        }
    }
}

extern "C" void kernel_launch(void* const* d_in, const int* in_sizes, int n_in,
                              void* d_out, int out_size, void* d_ws, size_t ws_size,
                              hipStream_t stream) {
    const float* tensor    = (const float*)d_in[0];  // (8, 4096, 1024) fp32
    const int*   sel_idx   = (const int*)d_in[1];    // (8, 2) int32
    const float* sel_probs = (const float*)d_in[2];  // (8, 2) fp32
    const float* W         = (const float*)d_in[3];  // (16, 1024, 1024) fp32
    const float* bias      = (const float*)d_in[4];  // (16, 1024) fp32
    float* out = (float*)d_out;                      // (8, 4096, 16, 64) fp32

    unsigned short* wpack = (unsigned short*)d_ws;                    // 16 MiB bf16
    float* beff = (float*)((char*)d_ws + (size_t)B_ * DM * DO * 2);   // 32 KiB fp32

    hipLaunchKernelGGL(prep_wpack, dim3(32, 8, 8), dim3(256), 0, stream,
                       W, sel_idx, sel_probs, wpack);
    hipLaunchKernelGGL(prep_beff, dim3(8), dim3(256), 0, stream,
                       bias, sel_idx, sel_probs, beff);
    hipLaunchKernelGGL(gemm_bias_sigmoid, dim3(8, 32, 8), dim3(256), 0, stream,
                       tensor, wpack, beff, out);
}

// Round 2
// 163.836 us; speedup vs baseline: 1.2029x; 1.2029x over previous
//
#include <hip/hip_runtime.h>
#include <hip/hip_bf16.h>

#define B_  8
#define S_  4096
#define DM  1024
#define DO  1024

typedef __attribute__((ext_vector_type(4))) float f32x4;
typedef __attribute__((ext_vector_type(8))) short bf16x8;

__device__ inline unsigned int pkbf(float a, float b) {
    __hip_bfloat162 h = __float22bfloat162_rn(float2{a, b});
    union { __hip_bfloat162 h2; unsigned int u; } cv;
    cv.h2 = h;
    return cv.u;
}

// ---- prep: wpack[b][nb][kt][half][colh:128][k-swizzled:64] bf16 ----
// Pre-swizzled LDS image: 16-byte k-group g of row colh stored at slot
// g ^ (colh & 7). GEMM stages this linearly via global_load_lds and applies
// the same XOR on ds_read (rule 21: source perm == read perm).
__global__ __launch_bounds__(256) void prep_wpack(
    const float* __restrict__ W, const int* __restrict__ sel_idx,
    const float* __restrict__ sel_probs, unsigned short* __restrict__ wpack)
{
    const int kt = blockIdx.x, nb = blockIdx.y, b = blockIdx.z;
    const int i0 = sel_idx[b*2+0], i1 = sel_idx[b*2+1];
    const float p0 = sel_probs[b*2+0], p1 = sel_probs[b*2+1];
    const int col = threadIdx.x;              // 0..255
    const int half = col >> 7, colh = col & 127;

    const float* w0 = W + (size_t)i0 * DM * DO + (size_t)(kt * 64) * DO + nb * 256 + col;
    const float* w1 = W + (size_t)i1 * DM * DO + (size_t)(kt * 64) * DO + nb * 256 + col;

    char* dst = (char*)wpack + ((((size_t)b * 4 + nb) * 16 + kt) << 15)
              + half * 16384 + colh * 128;

    #pragma unroll
    for (int g = 0; g < 8; ++g) {
        float v[8];
        #pragma unroll
        for (int j = 0; j < 8; ++j)
            v[j] = p0 * w0[(size_t)(g * 8 + j) * DO] + p1 * w1[(size_t)(g * 8 + j) * DO];
        uint4 u;
        u.x = pkbf(v[0], v[1]); u.y = pkbf(v[2], v[3]);
        u.z = pkbf(v[4], v[5]); u.w = pkbf(v[6], v[7]);
        *reinterpret_cast<uint4*>(dst + ((g * 16) ^ ((colh & 7) << 4))) = u;
    }
}

// ---- prep: b_eff[b][o] ----
__global__ __launch_bounds__(256) void prep_beff(
    const float* __restrict__ bias, const int* __restrict__ sel_idx,
    const float* __restrict__ sel_probs, float* __restrict__ beff)
{
    const int b = blockIdx.x;
    const int i0 = sel_idx[b*2+0], i1 = sel_idx[b*2+1];
    const float p0 = sel_probs[b*2+0], p1 = sel_probs[b*2+1];
    for (int o = threadIdx.x; o < DO; o += blockDim.x)
        beff[(size_t)b * DO + o] = p0 * bias[(size_t)i0 * DO + o]
                                 + p1 * bias[(size_t)i1 * DO + o];
}

// ---- GEMM: 256x256 tile, BK=64, 8 waves (2M x 4N), double-buffered 128KB LDS,
// 4 phases/K-step, T2 swizzle, T5 setprio, T14 async A-staging (fp32->bf16). ----
__global__ __launch_bounds__(512, 1) void gemm8(
    const float* __restrict__ X, const unsigned short* __restrict__ wpack,
    const float* __restrict__ beff, float* __restrict__ out)
{
    extern __shared__ char lds[];   // 2 bufs x 64KB: A[32KB: half][rowh:128][kswz], B at +32768 same

    // XCD chunked swizzle (512 blocks, 8 XCDs): XCD x gets ids x*64..x*64+63,
    // all same batch b -> wpack (2MB) L2-resident; nb-neighbors share X stripe.
    const int id = blockIdx.x;
    const int swz = (id & 7) * 64 + (id >> 3);
    const int b  = swz >> 6;
    const int bm = (swz & 63) >> 2;
    const int nb = swz & 3;

    const int t = threadIdx.x;
    const int wave = t >> 6, lane = t & 63;
    const int wm = wave >> 2, wn = wave & 3;       // 2 x 4 wave grid, 128x64 out each
    const int fr = lane & 15, fq = lane >> 4;

    // A staging map: per pass p(0..3): row = p*64 + (t>>3), k-group g = t&7
    const int s_row = t >> 3;                      // 0..63
    const int s_g   = t & 7;
    const float* xbase = X + ((size_t)(b * S_ + bm * 256 + s_row)) * DM + s_g * 8;

    // B staging: wave stages 4KB: instr i(0..3) at wave*4096 + i*1024
    const unsigned short* wtile0 = wpack + (((size_t)b * 4 + nb) * 16) * 16384;

    // fragment read offsets (swizzle XOR operand is thread-constant: fr&7)
    const int swz0 = (fq * 16) ^ ((fr & 7) << 4);        // ks=0
    const int swz1 = (64 + fq * 16) ^ ((fr & 7) << 4);   // ks=1
    const int aTbase = wm * 16384 + fr * 128;                          // + mf*2048 + swz
    const int bTbase = 32768 + (wn >> 1) * 16384 + ((wn & 1) * 64 + fr) * 128; // + nf*2048 + swz

    f32x4 acc[8][4] = {};
    float4 ax[8];

    // ---------- prologue: stage kt=0 into buf0 ----------
    #pragma unroll
    for (int p = 0; p < 4; ++p) {
        ax[p * 2]     = *reinterpret_cast<const float4*>(xbase + (size_t)p * 64 * DM);
        ax[p * 2 + 1] = *reinterpret_cast<const float4*>(xbase + (size_t)p * 64 * DM + 4);
    }
    {
        const char* gB = (const char*)wtile0;
        #pragma unroll
        for (int i = 0; i < 4; ++i)
            __builtin_amdgcn_global_load_lds(
                (const __attribute__((address_space(1))) void*)(gB + wave * 4096 + i * 1024 + lane * 16),
                (__attribute__((address_space(3))) void*)(lds + 32768 + wave * 4096 + i * 1024),
                16, 0, 0);
    }
    #pragma unroll
    for (int p = 0; p < 4; ++p) {
        const int row = p * 64 + s_row;
        const int half = row >> 7, rowh = row & 127;
        uint4 u;
        u.x = pkbf(ax[p*2].x, ax[p*2].y);     u.y = pkbf(ax[p*2].z, ax[p*2].w);
        u.z = pkbf(ax[p*2+1].x, ax[p*2+1].y); u.w = pkbf(ax[p*2+1].z, ax[p*2+1].w);
        *reinterpret_cast<uint4*>(lds + half * 16384 + rowh * 128
                                  + ((s_g * 16) ^ ((rowh & 7) << 4))) = u;
    }
    __syncthreads();   // drains vmcnt (B gload_lds) + lgkm (A ds_writes), full fence

    // ---------- main loop ----------
    for (int kt = 0; kt < 16; ++kt) {
        char* bufc = lds + (kt & 1) * 65536;
        char* bufn = lds + ((kt + 1) & 1) * 65536;

        // phase-0 head: issue next K-tile staging (lands ~4 phases later)
        if (kt < 15) {
            #pragma unroll
            for (int p = 0; p < 4; ++p) {
                ax[p * 2]     = *reinterpret_cast<const float4*>(xbase + (size_t)p * 64 * DM + (kt + 1) * 64);
                ax[p * 2 + 1] = *reinterpret_cast<const float4*>(xbase + (size_t)p * 64 * DM + (kt + 1) * 64 + 4);
            }
            const char* gB = (const char*)(wtile0 + (size_t)(kt + 1) * 16384);
            #pragma unroll
            for (int i = 0; i < 4; ++i)
                __builtin_amdgcn_global_load_lds(
                    (const __attribute__((address_space(1))) void*)(gB + wave * 4096 + i * 1024 + lane * 16),
                    (__attribute__((address_space(3))) void*)(bufn + 32768 + wave * 4096 + i * 1024),
                    16, 0, 0);
        }

        // B fragments for the whole K-step (held in regs across phases)
        bf16x8 bfrag[4][2];
        #pragma unroll
        for (int nf = 0; nf < 4; ++nf) {
            bfrag[nf][0] = *reinterpret_cast<const bf16x8*>(bufc + bTbase + nf * 2048 + swz0);
            bfrag[nf][1] = *reinterpret_cast<const bf16x8*>(bufc + bTbase + nf * 2048 + swz1);
        }

        // 4 phases x (2 m-frags x 4 n-frags x 2 ks) = 64 MFMA
        #pragma unroll
        for (int p = 0; p < 4; ++p) {
            bf16x8 af[2][2];
            #pragma unroll
            for (int i = 0; i < 2; ++i) {
                af[i][0] = *reinterpret_cast<const bf16x8*>(bufc + aTbase + (2*p + i) * 2048 + swz0);
                af[i][1] = *reinterpret_cast<const bf16x8*>(bufc + aTbase + (2*p + i) * 2048 + swz1);
            }
            __builtin_amdgcn_s_barrier();
            __builtin_amdgcn_s_setprio(1);
            #pragma unroll
            for (int i = 0; i < 2; ++i) {
                #pragma unroll
                for (int nf = 0; nf < 4; ++nf) {
                    acc[2*p+i][nf] = __builtin_amdgcn_mfma_f32_16x16x32_bf16(af[i][0], bfrag[nf][0], acc[2*p+i][nf], 0, 0, 0);
                    acc[2*p+i][nf] = __builtin_amdgcn_mfma_f32_16x16x32_bf16(af[i][1], bfrag[nf][1], acc[2*p+i][nf], 0, 0, 0);
                }
            }
            __builtin_amdgcn_s_setprio(0);
            __builtin_amdgcn_s_barrier();
        }

        // K-step tail: convert + write A for kt+1 (loads are ~4 phases old)
        if (kt < 15) {
            #pragma unroll
            for (int p = 0; p < 4; ++p) {
                const int row = p * 64 + s_row;
                const int half = row >> 7, rowh = row & 127;
                uint4 u;
                u.x = pkbf(ax[p*2].x, ax[p*2].y);     u.y = pkbf(ax[p*2].z, ax[p*2].w);
                u.z = pkbf(ax[p*2+1].x, ax[p*2+1].y); u.w = pkbf(ax[p*2+1].z, ax[p*2+1].w);
                *reinterpret_cast<uint4*>(bufn + half * 16384 + rowh * 128
                                          + ((s_g * 16) ^ ((rowh & 7) << 4))) = u;
            }
        }
        __syncthreads();   // drains vmcnt(0)+lgkmcnt(0); all of buf[kt+1] valid after this
    }

    // ---------- epilogue: bias + sigmoid, fp32 store ----------
    const float* be = beff + (size_t)b * DO + nb * 256 + wn * 64;
    float bv[4];
    #pragma unroll
    for (int nf = 0; nf < 4; ++nf) bv[nf] = be[nf * 16 + fr];

    float* ob = out + ((size_t)(b * S_ + bm * 256 + wm * 128)) * DO + nb * 256 + wn * 64;
    #pragma unroll
    for (int mf = 0; mf < 8; ++mf) {
        #pragma unroll
        for (int nf = 0; nf < 4; ++nf) {
            const int col = nf * 16 + fr;
            #pragma unroll
            for (int r = 0; r < 4; ++r) {
                const int row = mf * 16 + fq * 4 + r;
                const float xv = acc[mf][nf][r] + bv[nf];
                ob[(size_t)row * DO + col] = 1.0f / (1.0f + __expf(-xv));
            }
        }
    }
}

extern "C" void kernel_launch(void* const* d_in, const int* in_sizes, int n_in,
                              void* d_out, int out_size, void* d_ws, size_t ws_size,
                              hipStream_t stream) {
    const float* tensor    = (const float*)d_in[0];  // (8, 4096, 1024) fp32
    const int*   sel_idx   = (const int*)d_in[1];    // (8, 2) int32
    const float* sel_probs = (const float*)d_in[2];  // (8, 2) fp32
    const float* W         = (const float*)d_in[3];  // (16, 1024, 1024) fp32
    const float* bias      = (const float*)d_in[4];  // (16, 1024) fp32
    float* out = (float*)d_out;                      // (8, 4096, 1024) fp32

    unsigned short* wpack = (unsigned short*)d_ws;                    // 16 MiB bf16 (swizzled pack)
    float* beff = (float*)((char*)d_ws + (size_t)B_ * 4 * 16 * 32768);// +32 KiB fp32

    // allow 128 KiB dynamic LDS (no-op if already permitted)
    static bool attr_set = false;
    if (!attr_set) {
        hipFuncSetAttribute((const void*)gemm8,
                            hipFuncAttributeMaxDynamicSharedMemorySize, 131072);
        attr_set = true;
    }

    hipLaunchKernelGGL(prep_wpack, dim3(16, 4, 8), dim3(256), 0, stream,
                       W, sel_idx, sel_probs, wpack);
    hipLaunchKernelGGL(prep_beff, dim3(8), dim3(256), 0, stream,
                       bias, sel_idx, sel_probs, beff);
    hipLaunchKernelGGL(gemm8, dim3(512), dim3(512), 131072, stream,
                       tensor, wpack, beff, out);
}

// Round 3
// 142.962 us; speedup vs baseline: 1.3785x; 1.1460x over previous
//
#include <hip/hip_runtime.h>
#include <hip/hip_bf16.h>

#define B_  8
#define S_  4096
#define DM  1024
#define DO  1024

typedef __attribute__((ext_vector_type(4))) float f32x4;
typedef __attribute__((ext_vector_type(8))) short bf16x8;

__device__ inline unsigned int pkbf(float a, float b) {
    __hip_bfloat162 h = __float22bfloat162_rn(float2{a, b});
    union { __hip_bfloat162 h2; unsigned int u; } cv;
    cv.h2 = h;
    return cv.u;
}

// ---- prep: wpack[b][nb][kt] 32KB tiles: [half][colh:128][k-swizzled 128B] bf16 ----
__global__ __launch_bounds__(256) void prep_wpack(
    const float* __restrict__ W, const int* __restrict__ sel_idx,
    const float* __restrict__ sel_probs, unsigned short* __restrict__ wpack)
{
    const int kt = blockIdx.x, nb = blockIdx.y, b = blockIdx.z;
    const int i0 = sel_idx[b*2+0], i1 = sel_idx[b*2+1];
    const float p0 = sel_probs[b*2+0], p1 = sel_probs[b*2+1];
    const int col = threadIdx.x;              // 0..255
    const int half = col >> 7, colh = col & 127;

    const float* w0 = W + (size_t)i0 * DM * DO + (size_t)(kt * 64) * DO + nb * 256 + col;
    const float* w1 = W + (size_t)i1 * DM * DO + (size_t)(kt * 64) * DO + nb * 256 + col;

    char* dst = (char*)wpack + ((((size_t)b * 4 + nb) * 16 + kt) << 15)
              + half * 16384 + colh * 128;

    #pragma unroll
    for (int g = 0; g < 8; ++g) {
        float v[8];
        #pragma unroll
        for (int j = 0; j < 8; ++j)
            v[j] = p0 * w0[(size_t)(g * 8 + j) * DO] + p1 * w1[(size_t)(g * 8 + j) * DO];
        uint4 u;
        u.x = pkbf(v[0], v[1]); u.y = pkbf(v[2], v[3]);
        u.z = pkbf(v[4], v[5]); u.w = pkbf(v[6], v[7]);
        *reinterpret_cast<uint4*>(dst + ((g * 16) ^ ((colh & 7) << 4))) = u;
    }
}

__global__ __launch_bounds__(256) void prep_beff(
    const float* __restrict__ bias, const int* __restrict__ sel_idx,
    const float* __restrict__ sel_probs, float* __restrict__ beff)
{
    const int b = blockIdx.x;
    const int i0 = sel_idx[b*2+0], i1 = sel_idx[b*2+1];
    const float p0 = sel_probs[b*2+0], p1 = sel_probs[b*2+1];
    for (int o = threadIdx.x; o < DO; o += blockDim.x)
        beff[(size_t)b * DO + o] = p0 * bias[(size_t)i0 * DO + o]
                                 + p1 * bias[(size_t)i1 * DO + o];
}

// ---- GEMM: 256x256, BK=64, 8 waves (2Mx4N). A single-buffer (32KB, tail-written),
// B triple-buffer (3x32KB) with 2-deep counted prefetch. No vmcnt(0) in loop. ----
__global__ __launch_bounds__(512, 1) void gemm8(
    const float* __restrict__ X, const unsigned short* __restrict__ wpack,
    const float* __restrict__ beff, float* __restrict__ out)
{
    extern __shared__ char lds[];   // A: [0,32KB)  B: 32KB + {0,1,2}*32KB

    const int id = blockIdx.x;
    const int swz = (id & 7) * 64 + (id >> 3);   // XCD-chunked (512 = 8*64, bijective)
    const int b  = swz >> 6;
    const int bm = (swz & 63) >> 2;
    const int nb = swz & 3;

    const int t = threadIdx.x;
    const int wave = t >> 6, lane = t & 63;
    const int wm = wave >> 2, wn = wave & 3;     // 2x4 grid, 128x64 out per wave
    const int fr = lane & 15, fq = lane >> 4;

    const int s_row = t >> 3;                    // A staging: 0..63
    const int s_g   = t & 7;
    const float* xbase = X + ((size_t)(b * S_ + bm * 256 + s_row)) * DM + s_g * 8;
    const char* wtile0 = (const char*)(wpack + (((size_t)b * 4 + nb) * 16) * 16384);

    const int swz0 = (fq * 16) ^ ((fr & 7) << 4);
    const int swz1 = (64 + fq * 16) ^ ((fr & 7) << 4);
    const int aTb = wm * 16384 + fr * 128;                               // + mf*2048 + swzK
    const int bTb = (wn >> 1) * 16384 + ((wn & 1) * 64 + fr) * 128;      // + boff + nf*2048 + swzK

    f32x4 acc[8][4] = {};
    float4 ax[8];

#define LOAD_X(KT)                                                            \
    _Pragma("unroll")                                                         \
    for (int p = 0; p < 4; ++p) {                                             \
        ax[p*2]   = *reinterpret_cast<const float4*>(xbase + (size_t)p*64*DM + (KT)*64);     \
        ax[p*2+1] = *reinterpret_cast<const float4*>(xbase + (size_t)p*64*DM + (KT)*64 + 4); \
    }

#define STAGE_B(KT, BOFF)                                                     \
    {                                                                         \
        const char* gB = wtile0 + (size_t)(KT) * 32768;                       \
        _Pragma("unroll")                                                     \
        for (int i = 0; i < 4; ++i)                                           \
            __builtin_amdgcn_global_load_lds(                                 \
                (const __attribute__((address_space(1))) void*)(gB + wave*4096 + i*1024 + lane*16), \
                (__attribute__((address_space(3))) void*)(lds + (BOFF) + wave*4096 + i*1024),       \
                16, 0, 0);                                                    \
    }

#define WRITE_A()                                                             \
    _Pragma("unroll")                                                         \
    for (int p = 0; p < 4; ++p) {                                             \
        const int row = p * 64 + s_row;                                       \
        const int half = row >> 7, rowh = row & 127;                          \
        uint4 u;                                                              \
        u.x = pkbf(ax[p*2].x, ax[p*2].y);     u.y = pkbf(ax[p*2].z, ax[p*2].w);     \
        u.z = pkbf(ax[p*2+1].x, ax[p*2+1].y); u.w = pkbf(ax[p*2+1].z, ax[p*2+1].w); \
        *reinterpret_cast<uint4*>(lds + half*16384 + rowh*128                 \
                                  + ((s_g*16) ^ ((rowh & 7) << 4))) = u;      \
    }

    // ---------- prologue ----------
    LOAD_X(0);
    __builtin_amdgcn_sched_barrier(0);
    STAGE_B(0, 32768);
    STAGE_B(1, 65536);
    __builtin_amdgcn_sched_barrier(0);
    WRITE_A();                                        // compiler: vmcnt(8) for ax use
    asm volatile("s_waitcnt vmcnt(4) lgkmcnt(0)" ::: "memory");  // B(0) done, B(1) in flight
    __builtin_amdgcn_s_barrier();

    int br = 32768, bmid = 65536, bw = 98304;

    for (int kt = 0; kt < 16; ++kt) {
        // head: issue next X (consumed at tail) and B two tiles ahead
        if (kt < 15) { LOAD_X(kt + 1); }
        __builtin_amdgcn_sched_barrier(0);
        if (kt < 14) { STAGE_B(kt + 2, bw); }
        __builtin_amdgcn_sched_barrier(0);

        const char* Bb = lds + br;
        bf16x8 bks[4], af[4];

#define PHASE(MFBASE, SK, RELOAD_B)                                           \
        {                                                                     \
            if (RELOAD_B) {                                                   \
                _Pragma("unroll")                                             \
                for (int nf = 0; nf < 4; ++nf)                                \
                    bks[nf] = *reinterpret_cast<const bf16x8*>(Bb + bTb + nf*2048 + (SK)); \
            }                                                                 \
            _Pragma("unroll")                                                 \
            for (int m = 0; m < 4; ++m)                                       \
                af[m] = *reinterpret_cast<const bf16x8*>(lds + aTb + ((MFBASE)+m)*2048 + (SK)); \
            __builtin_amdgcn_s_barrier();                                     \
            __builtin_amdgcn_s_setprio(1);                                    \
            _Pragma("unroll")                                                 \
            for (int m = 0; m < 4; ++m) {                                     \
                _Pragma("unroll")                                             \
                for (int nf = 0; nf < 4; ++nf)                                \
                    acc[(MFBASE)+m][nf] = __builtin_amdgcn_mfma_f32_16x16x32_bf16( \
                        af[m], bks[nf], acc[(MFBASE)+m][nf], 0, 0, 0);        \
            }                                                                 \
            __builtin_amdgcn_s_setprio(0);                                    \
            __builtin_amdgcn_s_barrier();                                     \
        }

        PHASE(0, swz0, 1)
        PHASE(4, swz0, 0)
        PHASE(0, swz1, 1)
        PHASE(4, swz1, 0)
#undef PHASE

        // tail: convert+write A for kt+1 into the (now idle) single A buffer.
        // ax consume -> compiler-counted vmcnt leaves B(kt+2) gloads in flight.
        if (kt < 15) {
            WRITE_A();
            asm volatile("s_waitcnt lgkmcnt(0)" ::: "memory");
            __builtin_amdgcn_s_barrier();
        }
        const int tmp = br; br = bmid; bmid = bw; bw = tmp;
    }

    // ---------- epilogue: bias + sigmoid, fp32 store ----------
    const float* be = beff + (size_t)b * DO + nb * 256 + wn * 64;
    float bv[4];
    #pragma unroll
    for (int nf = 0; nf < 4; ++nf) bv[nf] = be[nf * 16 + fr];

    float* ob = out + ((size_t)(b * S_ + bm * 256 + wm * 128)) * DO + nb * 256 + wn * 64;
    #pragma unroll
    for (int mf = 0; mf < 8; ++mf) {
        #pragma unroll
        for (int nf = 0; nf < 4; ++nf) {
            const int col = nf * 16 + fr;
            #pragma unroll
            for (int r = 0; r < 4; ++r) {
                const int row = mf * 16 + fq * 4 + r;
                const float xv = acc[mf][nf][r] + bv[nf];
                ob[(size_t)row * DO + col] = 1.0f / (1.0f + __expf(-xv));
            }
        }
    }
#undef LOAD_X
#undef STAGE_B
#undef WRITE_A
}

extern "C" void kernel_launch(void* const* d_in, const int* in_sizes, int n_in,
                              void* d_out, int out_size, void* d_ws, size_t ws_size,
                              hipStream_t stream) {
    const float* tensor    = (const float*)d_in[0];
    const int*   sel_idx   = (const int*)d_in[1];
    const float* sel_probs = (const float*)d_in[2];
    const float* W         = (const float*)d_in[3];
    const float* bias      = (const float*)d_in[4];
    float* out = (float*)d_out;

    unsigned short* wpack = (unsigned short*)d_ws;                     // 16 MiB
    float* beff = (float*)((char*)d_ws + (size_t)B_ * 4 * 16 * 32768); // +32 KiB

    hipFuncSetAttribute((const void*)gemm8,
                        hipFuncAttributeMaxDynamicSharedMemorySize, 131072);

    hipLaunchKernelGGL(prep_wpack, dim3(16, 4, 8), dim3(256), 0, stream,
                       W, sel_idx, sel_probs, wpack);
    hipLaunchKernelGGL(prep_beff, dim3(8), dim3(256), 0, stream,
                       bias, sel_idx, sel_probs, beff);
    hipLaunchKernelGGL(gemm8, dim3(512), dim3(512), 131072, stream,
                       tensor, wpack, beff, out);
}